// Round 7
// baseline (88.573 us; speedup 1.0000x reference)
//
#include <hip/hip_runtime.h>
#include <math.h>

#define MX 64
#define NC 4
#define NI 66          // MX + 2
#define NINT 62        // interior tridiagonal unknowns (c2..c63)

typedef _Float16 half4  __attribute__((ext_vector_type(4)));
typedef _Float16 half2v __attribute__((ext_vector_type(2)));

// ---------------------------------------------------------------------------
// Compile-time Thomas constants for the (1/6, 2/3, 1/6) tridiagonal system.
// ---------------------------------------------------------------------------
struct TC { float m[NINT]; float inv[NINT]; };
constexpr TC make_tc() {
    TC tc{};
    double dp = 2.0/3.0;
    tc.m[0] = 0.0f;
    tc.inv[0] = (float)(1.0/dp);
    for (int j = 1; j < NINT; ++j) {
        double m = (1.0/6.0) / dp;
        tc.m[j] = (float)m;
        dp = 2.0/3.0 - m*(1.0/6.0);
        tc.inv[j] = (float)(1.0/dp);
    }
    return tc;
}
__constant__ constexpr TC g_tc = make_tc();

// ---------------------------------------------------------------------------
// Fused coefficient solver: one block, 256 threads (unchanged from R4).
// ---------------------------------------------------------------------------
__global__ __launch_bounds__(256) void solve_fused(const float* __restrict__ data,
                                                   float4* __restrict__ coefsOut)
{
    __shared__ float cxS[NC][NI][65];   // 68,640 B
    __shared__ half4 chS[NI*NI];        // 34,848 B
    const int t = threadIdx.x;
    const float a = 1.0f/6.0f;

    // ---- Phase A: x-pass, one line per thread: t = (c, y) ----
    {
        const int c = t >> 6, y = t & 63;
        const float* g = data + c*(MX*MX) + y;
        float w[NINT];
        const float d0 = g[0];
        const float dM = g[63*MX];
        w[0] = g[1*MX] - a*d0;
        #pragma unroll
        for (int j = 1; j < NINT; ++j) {
            float r = g[(j+1)*MX];
            if (j == NINT-1) r -= a*dM;
            w[j] = r - g_tc.m[j]*w[j-1];
        }
        float x = w[NINT-1] * g_tc.inv[NINT-1];
        const float c63 = x;
        cxS[c][63][y] = x;
        #pragma unroll
        for (int j = NINT-2; j >= 0; --j) {
            x = (w[j] - a*x) * g_tc.inv[j];
            cxS[c][j+2][y] = x;
        }
        cxS[c][0][y]  = 2.0f*d0 - x;
        cxS[c][1][y]  = d0;
        cxS[c][64][y] = dM;
        cxS[c][65][y] = 2.0f*dM - c63;
    }
    __syncthreads();

    // ---- Phase B: y-pass, 264 lines over 256 threads; results -> chS ----
    for (int line = t; line < NC*NI; line += 256) {
        const int c = line / NI;
        const int i = line - c*NI;
        const float* g = &cxS[c][i][0];
        _Float16* o = ((_Float16*)&chS[i*NI]) + c;

        float w[NINT];
        const float d0 = g[0];
        const float dM = g[63];
        w[0] = g[1] - a*d0;
        #pragma unroll
        for (int j = 1; j < NINT; ++j) {
            float r = g[j+1];
            if (j == NINT-1) r -= a*dM;
            w[j] = r - g_tc.m[j]*w[j-1];
        }
        float x = w[NINT-1] * g_tc.inv[NINT-1];
        const float c63 = x;
        o[63*NC] = (_Float16)x;
        #pragma unroll
        for (int j = NINT-2; j >= 0; --j) {
            x = (w[j] - a*x) * g_tc.inv[j];
            o[(j+2)*NC] = (_Float16)x;
        }
        o[0*NC]  = (_Float16)(2.0f*d0 - x);
        o[1*NC]  = (_Float16)d0;
        o[64*NC] = (_Float16)dM;
        o[65*NC] = (_Float16)(2.0f*dM - c63);
    }
    __syncthreads();

    const float4* src = (const float4*)chS;
    for (int s = t; s < (NI*NI)/2; s += 256) coefsOut[s] = src[s];
}

// ---------------------------------------------------------------------------
// Interpolation. R4-R6 evidence says this kernel is STALL-bound (LDS gather
// latency, ~16 dependent ds_read_b64 per point), not VALU-issue-bound.
// R7: 4 points per thread, single pass, branch-free eval bodies -> four
// independent load/math chains in one scheduling region for the compiler
// to interleave. Pairs (tid, tid+S) keep both u-loads and both out-stores
// fully coalesced.
// ---------------------------------------------------------------------------
__device__ __forceinline__ float4 eval_pt(const half4* __restrict__ lds,
                                          float ux, float uy)
{
    const float unx = ux * 63.0f;
    const float uny = uy * 63.0f;

    // i = clamp(trunc(un), 0, 62); t = un - i   (== reference _axis_index)
    int ix = (int)unx; ix = ix > 62 ? 62 : ix; ix = ix < 0 ? 0 : ix;
    int iy = (int)uny; iy = iy > 62 ? 62 : iy; iy = iy < 0 ? 0 : iy;
    const float tx = unx - (float)ix;
    const float ty = uny - (float)iy;

    // packed (tx,ty) cubic basis, coefficients pre-divided by 6
    const half2v t = __builtin_bit_cast(half2v, __builtin_amdgcn_cvt_pkrtz(tx, ty));
    const half2v c16  = half2v{(_Float16)(1.0f/6.0f), (_Float16)(1.0f/6.0f)};
    const half2v ch   = half2v{(_Float16)0.5f,  (_Float16)0.5f};
    const half2v cnh  = half2v{(_Float16)-0.5f, (_Float16)-0.5f};
    const half2v cn16 = half2v{(_Float16)(-1.0f/6.0f), (_Float16)(-1.0f/6.0f)};
    const half2v cn1  = half2v{(_Float16)-1.0f, (_Float16)-1.0f};
    const half2v c23  = half2v{(_Float16)(2.0f/3.0f), (_Float16)(2.0f/3.0f)};

    const half2v t2 = t*t;
    half2v b0 = (cn16*t + ch)*t;  b0 = (b0 + cnh)*t + c16;
    half2v b1 = (ch*t + cn1)*t2 + c23;
    half2v b2 = (cnh*t + ch)*t;   b2 = (b2 + ch)*t + c16;
    half2v b3 = c16*(t*t2);

    const half2v by0 = __builtin_shufflevector(b0, b0, 1, 1);
    const half2v by1 = __builtin_shufflevector(b1, b1, 1, 1);
    const half2v by2 = __builtin_shufflevector(b2, b2, 1, 1);
    const half2v by3 = __builtin_shufflevector(b3, b3, 1, 1);
    const half2v bx[4] = {
        __builtin_shufflevector(b0, b0, 0, 0),
        __builtin_shufflevector(b1, b1, 0, 0),
        __builtin_shufflevector(b2, b2, 0, 0),
        __builtin_shufflevector(b3, b3, 0, 0),
    };

    const half4* r = lds + (ix*NI + iy);
    half2v t01, t23;
    #pragma unroll
    for (int ar = 0; ar < 4; ++ar) {
        const half4 c0 = r[ar*NI + 0];
        const half4 c1 = r[ar*NI + 1];
        const half4 c2 = r[ar*NI + 2];
        const half4 c3 = r[ar*NI + 3];
        half2v a01 = c0.lo*by0 + c1.lo*by1 + c2.lo*by2 + c3.lo*by3;
        half2v a23 = c0.hi*by0 + c1.hi*by1 + c2.hi*by2 + c3.hi*by3;
        if (ar == 0) { t01 = a01*bx[0];        t23 = a23*bx[0]; }
        else         { t01 = a01*bx[ar] + t01; t23 = a23*bx[ar] + t23; }
    }
    return make_float4((float)t01.x, (float)t01.y, (float)t23.x, (float)t23.y);
}

__global__ __launch_bounds__(512) void interp(const float4* __restrict__ u2,
                                              const half4* __restrict__ coefsH,
                                              float4* __restrict__ out, int NB)
{
    __shared__ half4 lds[NI*NI];
    for (int s = threadIdx.x; s < NI*NI; s += 512) lds[s] = coefsH[s];
    __syncthreads();

    const int tid = blockIdx.x*512 + threadIdx.x;   // [0, 524288)
    const int S   = gridDim.x * 512;
    const int bA  = tid;                            // always < NB (524288 <= 1e6)
    const int bB  = tid + S;
    const bool hasB = bB < NB;

    const float4 uA = u2[bA];
    const float4 uB = u2[hasB ? bB : bA];

    // four independent point evaluations in one branch-free region
    const float4 v0 = eval_pt(lds, uA.x, uA.y);
    const float4 v1 = eval_pt(lds, uA.z, uA.w);
    const float4 v2 = eval_pt(lds, uB.x, uB.y);
    const float4 v3 = eval_pt(lds, uB.z, uB.w);

    out[2*bA]   = v0;
    out[2*bA+1] = v1;
    if (hasB) {
        out[2*bB]   = v2;
        out[2*bB+1] = v3;
    }
}

extern "C" void kernel_launch(void* const* d_in, const int* in_sizes, int n_in,
                              void* d_out, int out_size, void* d_ws, size_t ws_size,
                              hipStream_t stream)
{
    const float* u    = (const float*)d_in[0];   // (B,2)
    const float* data = (const float*)d_in[1];   // (4,64,64)
    const int B  = in_sizes[0] / 2;              // 2,000,000
    const int NB = B / 2;                        // 1,000,000 point pairs

    float4* coefsQ = (float4*)d_ws;              // 34,848 B fp16 table

    solve_fused<<<1, 256, 0, stream>>>(data, coefsQ);
    interp<<<1024, 512, 0, stream>>>((const float4*)u, (const half4*)coefsQ,
                                     (float4*)d_out, NB);
}